// Round 18
// baseline (411.596 us; speedup 1.0000x reference)
//
#include <hip/hip_runtime.h>
#include <hip/hip_bf16.h>

typedef short bf16x8 __attribute__((ext_vector_type(8)));
typedef float f32x4 __attribute__((ext_vector_type(4)));

#define HID 128
#define NRAD 6

static __device__ __forceinline__ unsigned short f2bf(float f) {
    union { float f; unsigned u; } v; v.f = f;
    unsigned r = v.u + 0x7FFFu + ((v.u >> 16) & 1u);
    return (unsigned short)(r >> 16);
}

// pack two f32 -> two bf16 (RTNE) in one instruction
static __device__ __forceinline__ unsigned cvt_pk_bf16(float lo, float hi) {
    unsigned r;
    asm("v_cvt_pk_bf16_f32 %0, %1, %2" : "=v"(r) : "v"(lo), "v"(hi));
    return r;
}

static __device__ __forceinline__ float swishf(float z) {
    return z * __builtin_amdgcn_rcpf(1.0f + __expf(-z));
}

// ---------------------------------------------------------------------------
// Precompute (fused, 159 blocks x 256):
//   blocks 0..94   : P1[v] = emb[v]@W1 + b_lin  AND  P2[v] = emb[v]@W2
//   blocks 95..158 : Wt[n][k] = (bf16) w_lin[256+k][n]
//   block 0 thread 0 initializes the dynamic quarter-tile counter.
// ---------------------------------------------------------------------------
__global__ void precompute_kernel(const float* __restrict__ emb,
                                  const float* __restrict__ w_lin,
                                  const float* __restrict__ b_lin,
                                  float* __restrict__ P1,
                                  float* __restrict__ P2,
                                  unsigned short* __restrict__ Wt,
                                  int* counter, int cinit) {
    const int b = blockIdx.x;
    const int t = threadIdx.x;
    if (b == 0 && t == 0 && counter) *counter = cinit;
    if (b < 95) {
        const int v = b;
        const int col = t & 127;
        const float* W = w_lin + (t < 128 ? 0 : HID * HID);
        float acc = (t < 128) ? b_lin[col] : 0.0f;
        #pragma unroll 4
        for (int k = 0; k < HID; ++k)
            acc = fmaf(emb[v * HID + k], W[k * HID + col], acc);
        (t < 128 ? P1 : P2)[v * HID + col] = acc;
    } else {
        const int idx = (b - 95) * 256 + t;   // 0..16383
        const int kr = idx >> 7, n = idx & 127;
        Wt[n * HID + kr] = f2bf(w_lin[(2 * HID + kr) * HID + n]);
    }
}

// ---------------------------------------------------------------------------
// Persistent edge kernel (r16 tile body). Work unit = 16-edge QUARTER-TILE,
// grabbed PER-WAVE: lane 0 atomicAdd's the counter, value broadcast with
// __shfl(v,0) -> wave-uniform by construction (fixes r17's per-thread
// divergence bug). No barriers in the loop; waves free-run; tail imbalance
// bounded by 16 edges. cur/next/next2 pipeline hides the atomic latency.
// ---------------------------------------------------------------------------
__global__ __launch_bounds__(256, 1) void edge_kernel(
    const float* __restrict__ rbf, const int* __restrict__ ei,
    const int* __restrict__ ej, const int* __restrict__ x,
    const float* __restrict__ w_rbf, const float* __restrict__ b_rbf,
    const float* __restrict__ P1, const float* __restrict__ P2,
    const unsigned short* __restrict__ Wt,
    float* __restrict__ out, int E, int nqt, int* counter)
{
    __shared__ __align__(16) unsigned short sB[HID * HID];   // W3^T bf16, XOR-swizzled
    __shared__ __align__(16) float sOut[4 * 16 * 64];        // 16 KB per-wave half-tile

    const int t = threadIdx.x;
    const int w = t >> 6, l = t & 63, lr = l & 15, lg = l >> 4;

    // ---- one-time: sB staging + w_rbf^T MFMA A-fragments in registers ----
    {
        const uint4* g = (const uint4*)Wt;
        #pragma unroll
        for (int q = 0; q < 8; ++q) {
            int gi = q * 256 + t;                 // coalesced
            int n = gi >> 4, cc = gi & 15;
            uint4 v = g[gi];
            *(uint4*)((char*)sB + n * 256 + ((cc * 16) ^ ((n & 7) << 4))) = v;
        }
    }
    // wf6[f]: A[row=n=f*16+lr][k=lg*8..+8]; nonzero only for lg==0
    bf16x8 wf6[8];
    #pragma unroll
    for (int f = 0; f < 8; ++f) {
        union { unsigned short s[8]; bf16x8 v; } u8;
        const int n = f * 16 + lr;
        #pragma unroll
        for (int u = 0; u < 8; ++u) {
            float val = 0.f;
            if (lg == 0) val = (u < NRAD) ? w_rbf[u * HID + n]
                               : (u == 6 ? b_rbf[n] : 0.f);
            u8.s[u] = f2bf(val);
        }
        wf6[f] = u8.v;
    }
    __syncthreads();   // the ONLY barrier; sB never written again

    char* const myOut = (char*)(sOut + w * 16 * 64);    // wave-private 4KB
    char* const myR   = myOut;                          // rbuf overlay

    // ---- per-wave dynamic quarter-tile pipeline: cur / next / next2 ----
    int cur = blockIdx.x * 4 + w;
    int next;
    {
        int v = 0;
        if (l == 0 && counter) v = atomicAdd(counter, 1);
        next = counter ? __shfl(v, 0) : cur + gridDim.x * 4;
    }

    // ---- preload quarter-tile `cur` inputs (lane's edge = cur*16 + lr) ----
    float2 r01, r23, r45;
    int xi, xj;
    {
        const int e0 = min(cur * 16 + lr, E - 1);
        const float* rp = rbf + (size_t)e0 * NRAD;
        r01 = *(const float2*)rp;
        r23 = *(const float2*)(rp + 2);
        r45 = *(const float2*)(rp + 4);
        xi = x[ei[e0]];
        xj = x[ej[e0]];
    }

    while (cur < nqt) {
        const int base = cur * 16;               // wave's first edge

        // ---- EARLY: h=0 P1/P2 prefetch (xi/xj known; hides under r-phase)
        const float* p1 = P1 + xi * HID;
        const float* p2 = P2 + xj * HID;
        f32x4 a1[4], a2[4];
        #pragma unroll
        for (int fi = 0; fi < 4; ++fi) {
            const int n0 = fi * 16 + lg * 4;
            a1[fi] = *(const f32x4*)(p1 + n0);
            a2[fi] = *(const f32x4*)(p2 + n0);
        }

        // grab quarter-tile after next (latency hidden under this tile)
        int next2;
        {
            int v = 0;
            if (l == 0 && counter) v = atomicAdd(counter, 1);
            next2 = counter ? __shfl(v, 0) : next + gridDim.x * 4;
        }

        // first-hop gathers for quarter-tile `next`
        const int pn = (next < nqt) ? next : cur;   // clamp to valid
        const int en = min(pn * 16 + lr, E - 1);
        const int ni = ei[en];
        const int nj = ej[en];

        // ---- rfrag: B[k=lg*8..+8][col=edge lr]; nonzero only lg==0 ----
        union { unsigned u[4]; bf16x8 v; } rf;
        rf.u[0] = (lg == 0) ? cvt_pk_bf16(r01.x, r01.y) : 0u;
        rf.u[1] = (lg == 0) ? cvt_pk_bf16(r23.x, r23.y) : 0u;
        rf.u[2] = (lg == 0) ? cvt_pk_bf16(r45.x, r45.y) : 0u;
        rf.u[3] = (lg == 0) ? 0x00003F80u : 0u;   // {1.0bf, 0}: bias slot k=6

        // ---- rbf projection on the MATRIX pipe ----
        f32x4 dacc[8];
        #pragma unroll
        for (int f = 0; f < 8; ++f)
            dacc[f] = __builtin_amdgcn_mfma_f32_16x16x32_bf16(
                          wf6[f], rf.v, (f32x4){0.f, 0.f, 0.f, 0.f}, 0, 0, 0);

        // swish + pack + write rbuf: lane owns n=f*16+lg*4..+4 of edge lr
        #pragma unroll
        for (int f = 0; f < 8; ++f) {
            unsigned q0 = cvt_pk_bf16(swishf(dacc[f][0]), swishf(dacc[f][1]));
            unsigned q1 = cvt_pk_bf16(swishf(dacc[f][2]), swishf(dacc[f][3]));
            uint2 pk = {q0, q1};
            *(uint2*)(myR + lr * 256 + ((f * 32 + lg * 8) ^ ((lr & 7) << 4))) = pk;
        }
        // read this lane's W3 B-fragments (wave-synchronous exchange)
        bf16x8 af[4];
        #pragma unroll
        for (int kk = 0; kk < 4; ++kk)
            af[kk] = *(const bf16x8*)(myR + lr * 256 +
                        ((kk * 64 + lg * 16) ^ ((lr & 7) << 4)));

        // ---- h=1 P1/P2 prefetch (hides under h0 MFMA + epilogue) ----
        f32x4 b1[4], b2[4];
        #pragma unroll
        for (int fi = 0; fi < 4; ++fi) {
            const int n0 = 64 + fi * 16 + lg * 4;
            b1[fi] = *(const f32x4*)(p1 + n0);
            b2[fi] = *(const f32x4*)(p2 + n0);
        }

        // next quarter-tile's rbf + second gather hop (hidden under MFMAs)
        float2 q01, q23, q45;
        {
            const float* rp = rbf + (size_t)en * NRAD;
            q01 = *(const float2*)rp;
            q23 = *(const float2*)(rp + 2);
            q45 = *(const float2*)(rp + 4);
        }
        const int nxi = x[ni];
        const int nxj = x[nj];

        // ---- W3 MFMA + epilogue in two COLUMN-HALVES through 4KB buffer ----
        #pragma unroll
        for (int h = 0; h < 2; ++h) {
            #pragma unroll
            for (int fi = 0; fi < 4; ++fi) {
                const int f = h * 4 + fi;
                f32x4 acc = (f32x4){0.f, 0.f, 0.f, 0.f};
                const int rowB = f * 16 + lr;
                const int rB = rowB * 256, sw2 = (rowB & 7) << 4;
                #pragma unroll
                for (int kk = 0; kk < 4; ++kk) {
                    const int colb = kk * 64 + lg * 16;
                    bf16x8 bb = *(const bf16x8*)((const char*)sB + rB + (colb ^ sw2));
                    acc = __builtin_amdgcn_mfma_f32_16x16x32_bf16(bb, af[kk], acc, 0, 0, 0);
                }
                const f32x4 g1 = h ? b1[fi] : a1[fi];
                const f32x4 g2 = h ? b2[fi] : a2[fi];
                const int n0h = (fi * 16 + lg * 4);   // col within half (floats)
                f32x4 v;
                #pragma unroll
                for (int u = 0; u < 4; ++u)
                    v[u] = swishf(acc[u] + g1[u] + g2[u]);
                *(f32x4*)(myOut + lr * 256 + ((n0h * 4) ^ ((lr & 7) << 4))) = v;
            }

            // coalesced nt stores of this half: 16 lanes = 256B contiguous
            #pragma unroll
            for (int it = 0; it < 4; ++it) {
                const int idx = it * 64 + l;          // chunk in 16x16 grid
                const int row = idx >> 4, cc = idx & 15;
                const f32x4 v = *(const f32x4*)(myOut + row * 256 +
                                  ((cc * 16) ^ ((row & 7) << 4)));
                if (base + row < E)
                    __builtin_nontemporal_store(v,
                        (f32x4*)(out + (size_t)(base + row) * HID + h * 64 + cc * 4));
            }
        }

        // rotate pipeline registers
        r01 = q01; r23 = q23; r45 = q45;
        xi = nxi; xj = nxj;
        cur = next; next = next2;
    }
}

extern "C" void kernel_launch(void* const* d_in, const int* in_sizes, int n_in,
                              void* d_out, int out_size, void* d_ws, size_t ws_size,
                              hipStream_t stream) {
    const int*   x     = (const int*)  d_in[0];
    const float* rbf   = (const float*)d_in[1];
    const int*   ei    = (const int*)  d_in[2];
    const int*   ej    = (const int*)  d_in[3];
    const float* emb   = (const float*)d_in[4];
    const float* w_rbf = (const float*)d_in[5];
    const float* b_rbf = (const float*)d_in[6];
    const float* w_lin = (const float*)d_in[7];
    const float* b_lin = (const float*)d_in[8];
    float* out = (float*)d_out;
    const int E = in_sizes[2];

    // workspace: P1 (95*128 f32), P2, Wt (128x128 bf16), quarter-tile counter
    float* P1 = (float*)d_ws;
    float* P2 = (float*)((char*)d_ws + 49152);
    unsigned short* Wt = (unsigned short*)((char*)d_ws + 98304);
    int* counter = (ws_size >= 131072 + 64) ? (int*)((char*)d_ws + 131072)
                                            : nullptr;

    const int nqt = (E + 15) / 16;                  // 16-edge quarter-tiles
    const int nblk = (nqt + 3) / 4 < 768 ? (nqt + 3) / 4 : 768;

    hipLaunchKernelGGL(precompute_kernel, dim3(159), dim3(256), 0, stream,
                       emb, w_lin, b_lin, P1, P2, Wt, counter, nblk * 4);

    hipLaunchKernelGGL(edge_kernel, dim3(nblk), dim3(256), 0, stream,
                       rbf, ei, ej, x, w_rbf, b_rbf, P1, P2, Wt, out, E,
                       nqt, counter);
}

// Round 19
// 94.477 us; speedup vs baseline: 4.3566x; 4.3566x over previous
//
#include <hip/hip_runtime.h>
#include <hip/hip_bf16.h>

typedef short bf16x8 __attribute__((ext_vector_type(8)));
typedef float f32x4 __attribute__((ext_vector_type(4)));

#define HID 128
#define NRAD 6
#define TILE 64

static __device__ __forceinline__ unsigned short f2bf(float f) {
    union { float f; unsigned u; } v; v.f = f;
    unsigned r = v.u + 0x7FFFu + ((v.u >> 16) & 1u);
    return (unsigned short)(r >> 16);
}

// pack two f32 -> two bf16 (RTNE) in one instruction
static __device__ __forceinline__ unsigned cvt_pk_bf16(float lo, float hi) {
    unsigned r;
    asm("v_cvt_pk_bf16_f32 %0, %1, %2" : "=v"(r) : "v"(lo), "v"(hi));
    return r;
}

static __device__ __forceinline__ float swishf(float z) {
    return z * __builtin_amdgcn_rcpf(1.0f + __expf(-z));
}

// ---------------------------------------------------------------------------
// Precompute (fused, 159 blocks x 256):
//   blocks 0..94   : P1[v] = emb[v]@W1 + b_lin  AND  P2[v] = emb[v]@W2
//                    (threads 0..127 -> P1 col, 128..255 -> P2 col)
//   blocks 95..158 : Wt[n][k] = (bf16) w_lin[256+k][n]
// ---------------------------------------------------------------------------
__global__ void precompute_kernel(const float* __restrict__ emb,
                                  const float* __restrict__ w_lin,
                                  const float* __restrict__ b_lin,
                                  float* __restrict__ P1,
                                  float* __restrict__ P2,
                                  unsigned short* __restrict__ Wt) {
    const int b = blockIdx.x;
    const int t = threadIdx.x;
    if (b < 95) {
        const int v = b;
        const int col = t & 127;
        const float* W = w_lin + (t < 128 ? 0 : HID * HID);
        float acc = (t < 128) ? b_lin[col] : 0.0f;
        #pragma unroll 4
        for (int k = 0; k < HID; ++k)
            acc = fmaf(emb[v * HID + k], W[k * HID + col], acc);
        (t < 128 ? P1 : P2)[v * HID + col] = acc;
    } else {
        const int idx = (b - 95) * 256 + t;   // 0..16383
        const int kr = idx >> 7, n = idx & 127;
        Wt[n * HID + kr] = f2bf(w_lin[(2 * HID + kr) * HID + n]);
    }
}

// ---------------------------------------------------------------------------
// Persistent edge kernel (r16 static version — the measured optimum).
// Static grid-stride over 64-edge tiles (already optimally balanced; r18
// proved dynamic atomics cost 300us). MFMA rbf-projection (K padded 6->32,
// bias folded at k=6), wave-private rbuf exchange, x[]/rbf/P1/P2 software
// pipeline, column-half output staging + coalesced nt stores, 48KB LDS,
// 3 blocks/CU. NEW: s_setprio(1) around MFMA clusters (free-running waves
// -> scheduler can favor the MFMA-issuing wave; attn-regime T5).
// ---------------------------------------------------------------------------
__global__ __launch_bounds__(256, 1) void edge_kernel(
    const float* __restrict__ rbf, const int* __restrict__ ei,
    const int* __restrict__ ej, const int* __restrict__ x,
    const float* __restrict__ w_rbf, const float* __restrict__ b_rbf,
    const float* __restrict__ P1, const float* __restrict__ P2,
    const unsigned short* __restrict__ Wt,
    float* __restrict__ out, int E, int ntiles)
{
    __shared__ __align__(16) unsigned short sB[HID * HID];   // W3^T bf16, XOR-swizzled
    __shared__ __align__(16) float sOut[4 * 16 * 64];        // 16 KB per-wave half-tile

    const int t = threadIdx.x;
    const int w = t >> 6, l = t & 63, lr = l & 15, lg = l >> 4;

    // ---- one-time: sB staging + w_rbf^T MFMA A-fragments in registers ----
    {
        const uint4* g = (const uint4*)Wt;
        #pragma unroll
        for (int q = 0; q < 8; ++q) {
            int gi = q * 256 + t;                 // coalesced
            int n = gi >> 4, cc = gi & 15;
            uint4 v = g[gi];
            *(uint4*)((char*)sB + n * 256 + ((cc * 16) ^ ((n & 7) << 4))) = v;
        }
    }
    // wf6[f]: A[row=n=f*16+lr][k=lg*8..+8]; nonzero only for lg==0
    // (k=0..5 = w_rbf[k][n], k=6 = b_rbf bias slot, k=7 = 0)
    bf16x8 wf6[8];
    #pragma unroll
    for (int f = 0; f < 8; ++f) {
        union { unsigned short s[8]; bf16x8 v; } u8;
        const int n = f * 16 + lr;
        #pragma unroll
        for (int u = 0; u < 8; ++u) {
            float val = 0.f;
            if (lg == 0) val = (u < NRAD) ? w_rbf[u * HID + n]
                               : (u == 6 ? b_rbf[n] : 0.f);
            u8.s[u] = f2bf(val);
        }
        wf6[f] = u8.v;
    }
    __syncthreads();   // the ONLY barrier; sB never written again

    char* const myOut = (char*)(sOut + w * 16 * 64);    // wave-private 4KB
    char* const myR   = myOut;                          // rbuf overlay

    int tile = blockIdx.x;

    // ---- pipeline preload: tile 0 inputs (lane's edge = base + lr) ----
    float2 r01, r23, r45;
    int xi, xj;
    {
        const int b0 = tile * TILE + w * 16;
        const int e0 = min(b0 + lr, E - 1);
        const float* rp = rbf + (size_t)e0 * NRAD;
        r01 = *(const float2*)rp;
        r23 = *(const float2*)(rp + 2);
        r45 = *(const float2*)(rp + 4);
        xi = x[ei[e0]];
        xj = x[ej[e0]];
    }

    for (; tile < ntiles; tile += gridDim.x) {
        const int base = tile * TILE + w * 16;   // wave's first edge

        // ---- EARLY: h=0 P1/P2 prefetch (xi/xj known; hides under r-phase)
        const float* p1 = P1 + xi * HID;
        const float* p2 = P2 + xj * HID;
        f32x4 a1[4], a2[4];
        #pragma unroll
        for (int fi = 0; fi < 4; ++fi) {
            const int n0 = fi * 16 + lg * 4;
            a1[fi] = *(const f32x4*)(p1 + n0);
            a2[fi] = *(const f32x4*)(p2 + n0);
        }

        // issue next tile's ei/ej early (first gather hop)
        const int tn = tile + gridDim.x;
        const int tnb = (tn < ntiles ? tn : tile) * TILE + w * 16;
        const int en = min(tnb + lr, E - 1);
        const int ni = ei[en];
        const int nj = ej[en];

        // ---- rfrag: B[k=lg*8..+8][col=edge lr]; nonzero only lg==0 ----
        union { unsigned u[4]; bf16x8 v; } rf;
        rf.u[0] = (lg == 0) ? cvt_pk_bf16(r01.x, r01.y) : 0u;
        rf.u[1] = (lg == 0) ? cvt_pk_bf16(r23.x, r23.y) : 0u;
        rf.u[2] = (lg == 0) ? cvt_pk_bf16(r45.x, r45.y) : 0u;
        rf.u[3] = (lg == 0) ? 0x00003F80u : 0u;   // {1.0bf, 0}: bias slot k=6

        // ---- rbf projection on the MATRIX pipe ----
        f32x4 dacc[8];
        __builtin_amdgcn_s_setprio(1);
        #pragma unroll
        for (int f = 0; f < 8; ++f)
            dacc[f] = __builtin_amdgcn_mfma_f32_16x16x32_bf16(
                          wf6[f], rf.v, (f32x4){0.f, 0.f, 0.f, 0.f}, 0, 0, 0);
        __builtin_amdgcn_s_setprio(0);

        // swish + pack + write rbuf: lane owns n=f*16+lg*4..+4 of edge lr
        #pragma unroll
        for (int f = 0; f < 8; ++f) {
            unsigned q0 = cvt_pk_bf16(swishf(dacc[f][0]), swishf(dacc[f][1]));
            unsigned q1 = cvt_pk_bf16(swishf(dacc[f][2]), swishf(dacc[f][3]));
            uint2 pk = {q0, q1};
            *(uint2*)(myR + lr * 256 + ((f * 32 + lg * 8) ^ ((lr & 7) << 4))) = pk;
        }
        // read this lane's W3 B-fragments (wave-synchronous exchange)
        bf16x8 af[4];
        #pragma unroll
        for (int kk = 0; kk < 4; ++kk)
            af[kk] = *(const bf16x8*)(myR + lr * 256 +
                        ((kk * 64 + lg * 16) ^ ((lr & 7) << 4)));

        // ---- h=1 P1/P2 prefetch (hides under h0 MFMA + epilogue) ----
        f32x4 b1[4], b2[4];
        #pragma unroll
        for (int fi = 0; fi < 4; ++fi) {
            const int n0 = 64 + fi * 16 + lg * 4;
            b1[fi] = *(const f32x4*)(p1 + n0);
            b2[fi] = *(const f32x4*)(p2 + n0);
        }

        // next-tile rbf loads + second gather hop (hidden under MFMA phase)
        float2 q01, q23, q45;
        {
            const float* rp = rbf + (size_t)en * NRAD;
            q01 = *(const float2*)rp;
            q23 = *(const float2*)(rp + 2);
            q45 = *(const float2*)(rp + 4);
        }
        const int nxi = x[ni];
        const int nxj = x[nj];

        // ---- W3 MFMA + epilogue in two COLUMN-HALVES through 4KB buffer ----
        #pragma unroll
        for (int h = 0; h < 2; ++h) {
            #pragma unroll
            for (int fi = 0; fi < 4; ++fi) {
                const int f = h * 4 + fi;
                f32x4 acc = (f32x4){0.f, 0.f, 0.f, 0.f};
                const int rowB = f * 16 + lr;
                const int rB = rowB * 256, sw2 = (rowB & 7) << 4;
                __builtin_amdgcn_s_setprio(1);
                #pragma unroll
                for (int kk = 0; kk < 4; ++kk) {
                    const int colb = kk * 64 + lg * 16;
                    bf16x8 bb = *(const bf16x8*)((const char*)sB + rB + (colb ^ sw2));
                    acc = __builtin_amdgcn_mfma_f32_16x16x32_bf16(bb, af[kk], acc, 0, 0, 0);
                }
                __builtin_amdgcn_s_setprio(0);
                const f32x4 g1 = h ? b1[fi] : a1[fi];
                const f32x4 g2 = h ? b2[fi] : a2[fi];
                const int n0h = (fi * 16 + lg * 4);   // col within half (floats)
                f32x4 v;
                #pragma unroll
                for (int u = 0; u < 4; ++u)
                    v[u] = swishf(acc[u] + g1[u] + g2[u]);
                *(f32x4*)(myOut + lr * 256 + ((n0h * 4) ^ ((lr & 7) << 4))) = v;
            }

            // coalesced nt stores of this half: 16 lanes = 256B contiguous
            #pragma unroll
            for (int it = 0; it < 4; ++it) {
                const int idx = it * 64 + l;          // chunk in 16x16 grid
                const int row = idx >> 4, cc = idx & 15;
                const f32x4 v = *(const f32x4*)(myOut + row * 256 +
                                  ((cc * 16) ^ ((row & 7) << 4)));
                if (base + row < E)
                    __builtin_nontemporal_store(v,
                        (f32x4*)(out + (size_t)(base + row) * HID + h * 64 + cc * 4));
            }
        }

        // rotate pipeline registers
        r01 = q01; r23 = q23; r45 = q45;
        xi = nxi; xj = nxj;
    }
}

extern "C" void kernel_launch(void* const* d_in, const int* in_sizes, int n_in,
                              void* d_out, int out_size, void* d_ws, size_t ws_size,
                              hipStream_t stream) {
    const int*   x     = (const int*)  d_in[0];
    const float* rbf   = (const float*)d_in[1];
    const int*   ei    = (const int*)  d_in[2];
    const int*   ej    = (const int*)  d_in[3];
    const float* emb   = (const float*)d_in[4];
    const float* w_rbf = (const float*)d_in[5];
    const float* b_rbf = (const float*)d_in[6];
    const float* w_lin = (const float*)d_in[7];
    const float* b_lin = (const float*)d_in[8];
    float* out = (float*)d_out;
    const int E = in_sizes[2];

    // workspace: P1 (95*128 f32), P2, Wt (128x128 bf16)
    float* P1 = (float*)d_ws;
    float* P2 = (float*)((char*)d_ws + 49152);
    unsigned short* Wt = (unsigned short*)((char*)d_ws + 98304);

    hipLaunchKernelGGL(precompute_kernel, dim3(159), dim3(256), 0, stream,
                       emb, w_lin, b_lin, P1, P2, Wt);

    const int ntiles = (E + TILE - 1) / TILE;
    const int nblk = ntiles < 768 ? ntiles : 768;   // 3 blocks/CU resident
    hipLaunchKernelGGL(edge_kernel, dim3(nblk), dim3(256), 0, stream,
                       rbf, ei, ej, x, w_rbf, b_rbf, P1, P2, Wt, out, E, ntiles);
}

// Round 20
// 90.950 us; speedup vs baseline: 4.5255x; 1.0388x over previous
//
#include <hip/hip_runtime.h>
#include <hip/hip_bf16.h>

typedef short bf16x8 __attribute__((ext_vector_type(8)));
typedef float f32x4 __attribute__((ext_vector_type(4)));

#define HID 128
#define NRAD 6
#define TILE 64

static __device__ __forceinline__ unsigned short f2bf(float f) {
    union { float f; unsigned u; } v; v.f = f;
    unsigned r = v.u + 0x7FFFu + ((v.u >> 16) & 1u);
    return (unsigned short)(r >> 16);
}

// pack two f32 -> two bf16 (RTNE) in one instruction
static __device__ __forceinline__ unsigned cvt_pk_bf16(float lo, float hi) {
    unsigned r;
    asm("v_cvt_pk_bf16_f32 %0, %1, %2" : "=v"(r) : "v"(lo), "v"(hi));
    return r;
}

static __device__ __forceinline__ float swishf(float z) {
    return z * __builtin_amdgcn_rcpf(1.0f + __expf(-z));
}

// ---------------------------------------------------------------------------
// Precompute (fused, 159 blocks x 256):
//   blocks 0..94   : P1[v] = emb[v]@W1 + b_lin  AND  P2[v] = emb[v]@W2
//   blocks 95..158 : Wt[n][k] = (bf16) w_lin[256+k][n]
// ---------------------------------------------------------------------------
__global__ void precompute_kernel(const float* __restrict__ emb,
                                  const float* __restrict__ w_lin,
                                  const float* __restrict__ b_lin,
                                  float* __restrict__ P1,
                                  float* __restrict__ P2,
                                  unsigned short* __restrict__ Wt) {
    const int b = blockIdx.x;
    const int t = threadIdx.x;
    if (b < 95) {
        const int v = b;
        const int col = t & 127;
        const float* W = w_lin + (t < 128 ? 0 : HID * HID);
        float acc = (t < 128) ? b_lin[col] : 0.0f;
        #pragma unroll 4
        for (int k = 0; k < HID; ++k)
            acc = fmaf(emb[v * HID + k], W[k * HID + col], acc);
        (t < 128 ? P1 : P2)[v * HID + col] = acc;
    } else {
        const int idx = (b - 95) * 256 + t;   // 0..16383
        const int kr = idx >> 7, n = idx & 127;
        Wt[n * HID + kr] = f2bf(w_lin[(2 * HID + kr) * HID + n]);
    }
}

// ---------------------------------------------------------------------------
// Persistent edge kernel (r19 base). NEW: h-phase overlap — compute h0's
// MFMA chains, stage h0 to LDS, then compute h1's chains BEFORE h0's
// store-loop (h1's 16 MFMAs cover h0's LDS write->read settle), then store
// h0, stage h1, store h1. Register peak unchanged (acc0 dies at its stage
// before acc1 is born); only the h0 store-loop moves later.
// Everything else identical to the measured 94.4us optimum.
// ---------------------------------------------------------------------------
__global__ __launch_bounds__(256, 1) void edge_kernel(
    const float* __restrict__ rbf, const int* __restrict__ ei,
    const int* __restrict__ ej, const int* __restrict__ x,
    const float* __restrict__ w_rbf, const float* __restrict__ b_rbf,
    const float* __restrict__ P1, const float* __restrict__ P2,
    const unsigned short* __restrict__ Wt,
    float* __restrict__ out, int E, int ntiles)
{
    __shared__ __align__(16) unsigned short sB[HID * HID];   // W3^T bf16, XOR-swizzled
    __shared__ __align__(16) float sOut[4 * 16 * 64];        // 16 KB per-wave half-tile

    const int t = threadIdx.x;
    const int w = t >> 6, l = t & 63, lr = l & 15, lg = l >> 4;

    // ---- one-time: sB staging + w_rbf^T MFMA A-fragments in registers ----
    {
        const uint4* g = (const uint4*)Wt;
        #pragma unroll
        for (int q = 0; q < 8; ++q) {
            int gi = q * 256 + t;                 // coalesced
            int n = gi >> 4, cc = gi & 15;
            uint4 v = g[gi];
            *(uint4*)((char*)sB + n * 256 + ((cc * 16) ^ ((n & 7) << 4))) = v;
        }
    }
    // wf6[f]: A[row=n=f*16+lr][k=lg*8..+8]; nonzero only for lg==0
    // (k=0..5 = w_rbf[k][n], k=6 = b_rbf bias slot, k=7 = 0)
    bf16x8 wf6[8];
    #pragma unroll
    for (int f = 0; f < 8; ++f) {
        union { unsigned short s[8]; bf16x8 v; } u8;
        const int n = f * 16 + lr;
        #pragma unroll
        for (int u = 0; u < 8; ++u) {
            float val = 0.f;
            if (lg == 0) val = (u < NRAD) ? w_rbf[u * HID + n]
                               : (u == 6 ? b_rbf[n] : 0.f);
            u8.s[u] = f2bf(val);
        }
        wf6[f] = u8.v;
    }
    __syncthreads();   // the ONLY barrier; sB never written again

    char* const myOut = (char*)(sOut + w * 16 * 64);    // wave-private 4KB
    char* const myR   = myOut;                          // rbuf overlay

    int tile = blockIdx.x;

    // ---- pipeline preload: tile 0 inputs (lane's edge = base + lr) ----
    float2 r01, r23, r45;
    int xi, xj;
    {
        const int b0 = tile * TILE + w * 16;
        const int e0 = min(b0 + lr, E - 1);
        const float* rp = rbf + (size_t)e0 * NRAD;
        r01 = *(const float2*)rp;
        r23 = *(const float2*)(rp + 2);
        r45 = *(const float2*)(rp + 4);
        xi = x[ei[e0]];
        xj = x[ej[e0]];
    }

    for (; tile < ntiles; tile += gridDim.x) {
        const int base = tile * TILE + w * 16;   // wave's first edge

        // ---- EARLY: h=0 P1/P2 prefetch (xi/xj known; hides under r-phase)
        const float* p1 = P1 + xi * HID;
        const float* p2 = P2 + xj * HID;
        f32x4 a1[4], a2[4];
        #pragma unroll
        for (int fi = 0; fi < 4; ++fi) {
            const int n0 = fi * 16 + lg * 4;
            a1[fi] = *(const f32x4*)(p1 + n0);
            a2[fi] = *(const f32x4*)(p2 + n0);
        }

        // issue next tile's ei/ej early (first gather hop)
        const int tn = tile + gridDim.x;
        const int tnb = (tn < ntiles ? tn : tile) * TILE + w * 16;
        const int en = min(tnb + lr, E - 1);
        const int ni = ei[en];
        const int nj = ej[en];

        // ---- rfrag: B[k=lg*8..+8][col=edge lr]; nonzero only lg==0 ----
        union { unsigned u[4]; bf16x8 v; } rf;
        rf.u[0] = (lg == 0) ? cvt_pk_bf16(r01.x, r01.y) : 0u;
        rf.u[1] = (lg == 0) ? cvt_pk_bf16(r23.x, r23.y) : 0u;
        rf.u[2] = (lg == 0) ? cvt_pk_bf16(r45.x, r45.y) : 0u;
        rf.u[3] = (lg == 0) ? 0x00003F80u : 0u;   // {1.0bf, 0}: bias slot k=6

        // ---- rbf projection on the MATRIX pipe ----
        f32x4 dacc[8];
        __builtin_amdgcn_s_setprio(1);
        #pragma unroll
        for (int f = 0; f < 8; ++f)
            dacc[f] = __builtin_amdgcn_mfma_f32_16x16x32_bf16(
                          wf6[f], rf.v, (f32x4){0.f, 0.f, 0.f, 0.f}, 0, 0, 0);
        __builtin_amdgcn_s_setprio(0);

        // swish + pack + write rbuf: lane owns n=f*16+lg*4..+4 of edge lr
        #pragma unroll
        for (int f = 0; f < 8; ++f) {
            unsigned q0 = cvt_pk_bf16(swishf(dacc[f][0]), swishf(dacc[f][1]));
            unsigned q1 = cvt_pk_bf16(swishf(dacc[f][2]), swishf(dacc[f][3]));
            uint2 pk = {q0, q1};
            *(uint2*)(myR + lr * 256 + ((f * 32 + lg * 8) ^ ((lr & 7) << 4))) = pk;
        }
        // read this lane's W3 B-fragments (wave-synchronous exchange)
        bf16x8 af[4];
        #pragma unroll
        for (int kk = 0; kk < 4; ++kk)
            af[kk] = *(const bf16x8*)(myR + lr * 256 +
                        ((kk * 64 + lg * 16) ^ ((lr & 7) << 4)));

        // ---- h=1 P1/P2 prefetch (hides under h0 MFMA phase) ----
        f32x4 b1[4], b2[4];
        #pragma unroll
        for (int fi = 0; fi < 4; ++fi) {
            const int n0 = 64 + fi * 16 + lg * 4;
            b1[fi] = *(const f32x4*)(p1 + n0);
            b2[fi] = *(const f32x4*)(p2 + n0);
        }

        // next-tile rbf loads + second gather hop (hidden under MFMA phase)
        float2 q01, q23, q45;
        {
            const float* rp = rbf + (size_t)en * NRAD;
            q01 = *(const float2*)rp;
            q23 = *(const float2*)(rp + 2);
            q45 = *(const float2*)(rp + 4);
        }
        const int nxi = x[ni];
        const int nxj = x[nj];

        // ==== h0 compute + stage ====
        __builtin_amdgcn_s_setprio(1);
        #pragma unroll
        for (int fi = 0; fi < 4; ++fi) {
            f32x4 acc = (f32x4){0.f, 0.f, 0.f, 0.f};
            const int rowB = fi * 16 + lr;
            const int rB = rowB * 256, sw2 = (rowB & 7) << 4;
            #pragma unroll
            for (int kk = 0; kk < 4; ++kk) {
                const int colb = kk * 64 + lg * 16;
                bf16x8 bb = *(const bf16x8*)((const char*)sB + rB + (colb ^ sw2));
                acc = __builtin_amdgcn_mfma_f32_16x16x32_bf16(bb, af[kk], acc, 0, 0, 0);
            }
            const int n0h = (fi * 16 + lg * 4);
            f32x4 v;
            #pragma unroll
            for (int u = 0; u < 4; ++u)
                v[u] = swishf(acc[u] + a1[fi][u] + a2[fi][u]);
            *(f32x4*)(myOut + lr * 256 + ((n0h * 4) ^ ((lr & 7) << 4))) = v;
        }

        // ==== h1 compute (covers h0's LDS write->read settle) ====
        f32x4 acc1[4];
        #pragma unroll
        for (int fi = 0; fi < 4; ++fi) {
            f32x4 acc = (f32x4){0.f, 0.f, 0.f, 0.f};
            const int rowB = (4 + fi) * 16 + lr;
            const int rB = rowB * 256, sw2 = (rowB & 7) << 4;
            #pragma unroll
            for (int kk = 0; kk < 4; ++kk) {
                const int colb = kk * 64 + lg * 16;
                bf16x8 bb = *(const bf16x8*)((const char*)sB + rB + (colb ^ sw2));
                acc = __builtin_amdgcn_mfma_f32_16x16x32_bf16(bb, af[kk], acc, 0, 0, 0);
            }
            acc1[fi] = acc;
        }
        __builtin_amdgcn_s_setprio(0);

        // ==== h0 store (coalesced nt; 16 lanes = 256B contiguous) ====
        #pragma unroll
        for (int it = 0; it < 4; ++it) {
            const int idx = it * 64 + l;
            const int row = idx >> 4, cc = idx & 15;
            const f32x4 v = *(const f32x4*)(myOut + row * 256 +
                              ((cc * 16) ^ ((row & 7) << 4)));
            if (base + row < E)
                __builtin_nontemporal_store(v,
                    (f32x4*)(out + (size_t)(base + row) * HID + cc * 4));
        }

        // ==== h1 stage ====
        #pragma unroll
        for (int fi = 0; fi < 4; ++fi) {
            const int n0h = (fi * 16 + lg * 4);
            f32x4 v;
            #pragma unroll
            for (int u = 0; u < 4; ++u)
                v[u] = swishf(acc1[fi][u] + b1[fi][u] + b2[fi][u]);
            *(f32x4*)(myOut + lr * 256 + ((n0h * 4) ^ ((lr & 7) << 4))) = v;
        }

        // ==== h1 store ====
        #pragma unroll
        for (int it = 0; it < 4; ++it) {
            const int idx = it * 64 + l;
            const int row = idx >> 4, cc = idx & 15;
            const f32x4 v = *(const f32x4*)(myOut + row * 256 +
                              ((cc * 16) ^ ((row & 7) << 4)));
            if (base + row < E)
                __builtin_nontemporal_store(v,
                    (f32x4*)(out + (size_t)(base + row) * HID + 64 + cc * 4));
        }

        // rotate pipeline registers
        r01 = q01; r23 = q23; r45 = q45;
        xi = nxi; xj = nxj;
    }
}

extern "C" void kernel_launch(void* const* d_in, const int* in_sizes, int n_in,
                              void* d_out, int out_size, void* d_ws, size_t ws_size,
                              hipStream_t stream) {
    const int*   x     = (const int*)  d_in[0];
    const float* rbf   = (const float*)d_in[1];
    const int*   ei    = (const int*)  d_in[2];
    const int*   ej    = (const int*)  d_in[3];
    const float* emb   = (const float*)d_in[4];
    const float* w_rbf = (const float*)d_in[5];
    const float* b_rbf = (const float*)d_in[6];
    const float* w_lin = (const float*)d_in[7];
    const float* b_lin = (const float*)d_in[8];
    float* out = (float*)d_out;
    const int E = in_sizes[2];

    // workspace: P1 (95*128 f32), P2, Wt (128x128 bf16)
    float* P1 = (float*)d_ws;
    float* P2 = (float*)((char*)d_ws + 49152);
    unsigned short* Wt = (unsigned short*)((char*)d_ws + 98304);

    hipLaunchKernelGGL(precompute_kernel, dim3(159), dim3(256), 0, stream,
                       emb, w_lin, b_lin, P1, P2, Wt);

    const int ntiles = (E + TILE - 1) / TILE;
    const int nblk = ntiles < 768 ? ntiles : 768;   // 3 blocks/CU resident
    hipLaunchKernelGGL(edge_kernel, dim3(nblk), dim3(256), 0, stream,
                       rbf, ei, ej, x, w_rbf, b_rbf, P1, P2, Wt, out, E, ntiles);
}